// Round 1
// baseline (276.454 us; speedup 1.0000x reference)
//
#include <hip/hip_runtime.h>

// CapsuleLayer fused kernel: priors GEMM (9-tap, K=128, N=512) + dynamic routing.
// Sizes fixed per reference: B=8, C=128, H=W=32, K=3, pad=1, stride=1 -> oh=ow=32,
// NC = NCAPS*CCH = 32*16 = 512, 3 routing iterations.

#define KK      3
#define CIN     128
#define NC      512
#define NCAPS   32
#define CCH     16
#define HS      32
#define WS      32
#define BB      8
#define PPOS    8      // w-positions per block
#define NT      128    // n-columns per block (8 capsules)
#define NTHREADS 128
#define NNPAD   132    // padded stride (floats) for priors rows -> breaks bank conflicts

__global__ __launch_bounds__(NTHREADS, 2)
void caps_fused(const float* __restrict__ in, const float* __restrict__ wgt,
                const float* __restrict__ bias, float* __restrict__ out) {
    // patch_s[row r][channel c][col] : rows h-1..h+1, cols w0-1..w0+8
    __shared__ float patch_s[3][CIN][PPOS + 2];          // 3*128*10*4 = 15360 B
    __shared__ float priors_s[PPOS * 9 * NNPAD];         // 8*9*132*4  = 38016 B

    const int blk   = blockIdx.x;
    const int nBlk  = blk & 3;           // 4 n-tiles of 128
    const int posBlk = blk >> 2;         // 1024 position blocks
    const int wBlk  = posBlk & 3;
    const int tmp   = posBlk >> 2;
    const int h     = tmp & 31;
    const int b     = tmp >> 5;
    const int w0    = wBlk * PPOS;
    const int n_base = nBlk * NT;
    const int t     = threadIdx.x;

    // ---- stage input patches into LDS (zero-padded borders) ----
    const int NPATCH = 3 * CIN * (PPOS + 2);             // 3840
    for (int e = t; e < NPATCH; e += NTHREADS) {
        int r    = e / (CIN * (PPOS + 2));
        int rest = e % (CIN * (PPOS + 2));
        int c    = rest / (PPOS + 2);
        int col  = rest % (PPOS + 2);
        int hh = h + r - 1;
        int ww = w0 + col - 1;
        float v = 0.f;
        if ((unsigned)hh < 32u && (unsigned)ww < 32u)
            v = in[(((b * CIN) + c) * HS + hh) * WS + ww];
        patch_s[r][c][col] = v;
    }
    __syncthreads();

    // ---- priors GEMM: thread t owns column nn = t for all 9 taps x 8 positions ----
    {
        const int nn = t;                 // 0..127
        float acc[3][3][PPOS];
        #pragma unroll
        for (int i = 0; i < 3; i++)
            #pragma unroll
            for (int j = 0; j < 3; j++) {
                float bv = bias[(i * 3 + j) * NC + n_base + nn];
                #pragma unroll
                for (int p = 0; p < PPOS; p++) acc[i][j][p] = bv;
            }
        const float* wp = wgt + n_base + nn;
        #pragma unroll 2
        for (int ch = 0; ch < CIN; ch++) {
            float wv[3][3];
            #pragma unroll
            for (int i = 0; i < 3; i++)
                #pragma unroll
                for (int j = 0; j < 3; j++)
                    wv[i][j] = wp[(size_t)((i * 3 + j) * CIN + ch) * NC];
            float pv[3][PPOS + 2];
            #pragma unroll
            for (int r = 0; r < 3; r++)
                #pragma unroll
                for (int col = 0; col < PPOS + 2; col++)
                    pv[r][col] = patch_s[r][ch][col];
            #pragma unroll
            for (int i = 0; i < 3; i++)
                #pragma unroll
                for (int j = 0; j < 3; j++)
                    #pragma unroll
                    for (int p = 0; p < PPOS; p++)
                        acc[i][j][p] += pv[i][j + p] * wv[i][j];
        }
        #pragma unroll
        for (int i = 0; i < 3; i++)
            #pragma unroll
            for (int j = 0; j < 3; j++)
                #pragma unroll
                for (int p = 0; p < PPOS; p++)
                    priors_s[(p * 9 + (i * 3 + j)) * NNPAD + nn] = acc[i][j][p];
    }
    __syncthreads();

    // ---- routing: 64 tasks = 8 capsules (within tile) x 8 positions ----
    if (t < (NT / CCH) * PPOS) {          // 64
        const int cap = t >> 3;           // 0..7 capsule within tile
        const int p   = t & 7;            // 0..7 position (consecutive lanes -> consecutive w)
        float pr[9][CCH];
        #pragma unroll
        for (int tap = 0; tap < 9; tap++)
            #pragma unroll
            for (int cc = 0; cc < CCH; cc++)
                pr[tap][cc] = priors_s[(p * 9 + tap) * NNPAD + cap * CCH + cc];

        float o[CCH];
        #pragma unroll
        for (int cc = 0; cc < CCH; cc++) {
            float s = 0.f;
            #pragma unroll
            for (int tap = 0; tap < 9; tap++) s += pr[tap][cc];
            o[cc] = s * (1.f / 9.f);
        }
        #pragma unroll
        for (int it = 0; it < 3; it++) {
            float cw[9];
            float S = 0.f;
            #pragma unroll
            for (int tap = 0; tap < 9; tap++) {
                float d2 = 0.f;
                #pragma unroll
                for (int cc = 0; cc < CCH; cc++) {
                    float d = o[cc] - pr[tap][cc];
                    d2 += d * d;
                }
                cw[tap] = rsqrtf(d2 + 1e-4f);
                S += cw[tap];
            }
            float inv = 1.f / S;
            #pragma unroll
            for (int cc = 0; cc < CCH; cc++) {
                float s = 0.f;
                #pragma unroll
                for (int tap = 0; tap < 9; tap++) s += pr[tap][cc] * cw[tap];
                o[cc] = s * inv;
            }
        }
        // ---- write output [B, NC, H, W] ----
        const int w = w0 + p;
        #pragma unroll
        for (int cc = 0; cc < CCH; cc++) {
            int n = n_base + cap * CCH + cc;
            out[(((size_t)b * NC + n) * HS + h) * WS + w] = o[cc];
        }
    }
}

extern "C" void kernel_launch(void* const* d_in, const int* in_sizes, int n_in,
                              void* d_out, int out_size, void* d_ws, size_t ws_size,
                              hipStream_t stream) {
    const float* in   = (const float*)d_in[0];
    const float* wgt  = (const float*)d_in[1];
    const float* bias = (const float*)d_in[2];
    float* out = (float*)d_out;

    // grid: 1024 position-blocks x 4 n-tiles
    dim3 grid(1024 * 4);
    dim3 block(NTHREADS);
    caps_fused<<<grid, block, 0, stream>>>(in, wgt, bias, out);
}

// Round 2
// 245.086 us; speedup vs baseline: 1.1280x; 1.1280x over previous
//
#include <hip/hip_runtime.h>

// CapsuleLayer fused: priors GEMM (9-tap, K=128 -> N=512) + dynamic routing,
// routing done fully in registers with 16-lane shuffle reductions.
// Fixed sizes: B=8, C=128, H=W=32, K=3, pad=1 -> oh=ow=32, NC=512, 3 iters.

#define CIN     128
#define NC      512
#define CCH     16
#define HS      32
#define WS      32
#define PPOS    8      // w-positions per block
#define NTHREADS 256   // covers 256 n-columns
#define ROWLEN  12     // padded patch row (10 used) -> 48B rows, 16B-aligned

__global__ __launch_bounds__(NTHREADS, 3)
void caps_fused(const float* __restrict__ in, const float* __restrict__ wgt,
                const float* __restrict__ bias, float* __restrict__ out) {
    __shared__ float patch_s[3][CIN][ROWLEN];   // 18432 B

    const int blk    = blockIdx.x;
    const int nBlk   = blk & 1;            // 2 n-tiles of 256
    const int posBlk = blk >> 1;           // 1024 position blocks
    const int wBlk   = posBlk & 3;
    const int tmp    = posBlk >> 2;
    const int h      = tmp & 31;
    const int b      = tmp >> 5;
    const int w0     = wBlk * PPOS;
    const int n_base = nBlk * NTHREADS;
    const int t      = threadIdx.x;
    const int nn     = t;                  // n-column owned by this thread

    // ---- stage input patches into LDS (zero-padded borders) ----
    for (int e = t; e < 3 * CIN * 10; e += NTHREADS) {
        int r    = e / (CIN * 10);
        int rest = e % (CIN * 10);
        int c    = rest / 10;
        int col  = rest % 10;
        int hh = h + r - 1;
        int ww = w0 + col - 1;
        float v = 0.f;
        if ((unsigned)hh < 32u && (unsigned)ww < 32u)
            v = in[(((b * CIN) + c) * HS + hh) * WS + ww];
        patch_s[r][c][col] = v;
    }
    __syncthreads();

    // ---- priors GEMM: thread owns column nn for 9 taps x 8 positions ----
    float acc[9][PPOS];
    #pragma unroll
    for (int tap = 0; tap < 9; tap++) {
        float bv = bias[tap * NC + n_base + nn];
        #pragma unroll
        for (int p = 0; p < PPOS; p++) acc[tap][p] = bv;
    }
    const float* wp = wgt + n_base + nn;
    #pragma unroll 2
    for (int ch = 0; ch < CIN; ch++) {
        float wv[9];
        #pragma unroll
        for (int tap = 0; tap < 9; tap++)
            wv[tap] = wp[(size_t)(tap * CIN + ch) * NC];
        float pv[3][10];
        #pragma unroll
        for (int r = 0; r < 3; r++)
            #pragma unroll
            for (int col = 0; col < 10; col++)
                pv[r][col] = patch_s[r][ch][col];
        #pragma unroll
        for (int i = 0; i < 3; i++)
            #pragma unroll
            for (int j = 0; j < 3; j++)
                #pragma unroll
                for (int p = 0; p < PPOS; p++)
                    acc[i * 3 + j][p] += pv[i][j + p] * wv[i * 3 + j];
    }

    // ---- routing in registers; Sum_cc d^2 via 16-lane butterfly shuffles ----
    float o[PPOS];
    #pragma unroll
    for (int p = 0; p < PPOS; p++) {
        float s = 0.f;
        #pragma unroll
        for (int tap = 0; tap < 9; tap++) s += acc[tap][p];
        o[p] = s * (1.f / 9.f);
    }
    #pragma unroll
    for (int it = 0; it < 3; it++) {
        #pragma unroll
        for (int p = 0; p < PPOS; p++) {
            float cw[9];
            float S = 0.f;
            #pragma unroll
            for (int tap = 0; tap < 9; tap++) {
                float d  = o[p] - acc[tap][p];
                float d2 = d * d;
                d2 += __shfl_xor(d2, 1);
                d2 += __shfl_xor(d2, 2);
                d2 += __shfl_xor(d2, 4);
                d2 += __shfl_xor(d2, 8);
                cw[tap] = rsqrtf(d2 + 1e-4f);
                S += cw[tap];
            }
            float inv = 1.f / S;
            float s = 0.f;
            #pragma unroll
            for (int tap = 0; tap < 9; tap++) s += acc[tap][p] * cw[tap];
            o[p] = s * inv;
        }
    }

    // ---- write output [B, NC, H, W]: 8 consecutive floats per thread ----
    const int n = n_base + nn;
    size_t base = ((size_t)b * NC + n) * (size_t)(HS * WS) + (size_t)h * WS + w0;
    #pragma unroll
    for (int p = 0; p < PPOS; p++) out[base + p] = o[p];
}

extern "C" void kernel_launch(void* const* d_in, const int* in_sizes, int n_in,
                              void* d_out, int out_size, void* d_ws, size_t ws_size,
                              hipStream_t stream) {
    const float* in   = (const float*)d_in[0];
    const float* wgt  = (const float*)d_in[1];
    const float* bias = (const float*)d_in[2];
    float* out = (float*)d_out;

    dim3 grid(1024 * 2);   // 1024 position-blocks x 2 n-tiles
    dim3 block(NTHREADS);
    caps_fused<<<grid, block, 0, stream>>>(in, wgt, bias, out);
}

// Round 3
// 118.748 us; speedup vs baseline: 2.3281x; 2.0639x over previous
//
#include <hip/hip_runtime.h>

// CapsuleLayer via bf16 MFMA, transposed orientation: C[n-channel][position].
// Fixed sizes: B=8, C=128, H=W=32, K=3, pad=1 -> oh=ow=32, NC=512, 3 routing iters.
//
// d_ws layout:
//   wT  : bf16 [9][512][128]      (weights, k(ch)-contiguous)        589824 elems
//   inT : bf16 [8][34][34][128]   (input, ch-last, zero-padded h,w)  1183744 elems

typedef __bf16 bf16x8 __attribute__((ext_vector_type(8)));
typedef float  f32x4  __attribute__((ext_vector_type(4)));

#define NC    512
#define CIN   128
#define HW    32
#define BB    8
#define INT_H 34
#define INT_W 34
#define WT_ELEMS (9 * NC * CIN)                    // 589824
#define INT_ELEMS (BB * INT_H * INT_W * CIN)       // 1183744

// ---- pre-pass 1: wT[tap][n][ch] bf16 <- wgt[tap][ch][n] fp32 ----
__global__ __launch_bounds__(256)
void transpose_w(const float* __restrict__ wgt, __bf16* __restrict__ wT) {
    int g   = blockIdx.x * 256 + threadIdx.x;   // 73728 threads
    int n   = g & 511;
    int cb  = (g >> 9) & 15;
    int tap = g >> 13;
    bf16x8 v;
    #pragma unroll
    for (int k = 0; k < 8; k++)
        v[k] = (__bf16)wgt[(tap * CIN + cb * 8 + k) * NC + n];
    *(bf16x8*)(wT + ((size_t)tap * NC + n) * CIN + cb * 8) = v;
}

// ---- pre-pass 2: inT[b][h+1][w+1][ch] bf16 <- input[b][ch][h][w] fp32 ----
__global__ __launch_bounds__(256)
void transpose_in(const float* __restrict__ in, __bf16* __restrict__ inT) {
    int g  = blockIdx.x * 256 + threadIdx.x;    // 131072 threads
    int w  = g & 31;
    int h  = (g >> 5) & 31;
    int cb = (g >> 10) & 15;
    int b  = g >> 14;
    bf16x8 v;
    #pragma unroll
    for (int k = 0; k < 8; k++)
        v[k] = (__bf16)in[((b * CIN + cb * 8 + k) * HW + h) * HW + w];
    *(bf16x8*)(inT + (((size_t)(b * INT_H + h + 1) * INT_W) + (w + 1)) * CIN + cb * 8) = v;
}

// ---- main: per block: 64 channels (4 capsules, 1/wave) x 32 positions (one h-row) ----
__global__ __launch_bounds__(256, 4)
void caps_main(const __bf16* __restrict__ wT, const __bf16* __restrict__ inT,
               const float* __restrict__ bias, float* __restrict__ out) {
    const int nblk = blockIdx.x & 7;
    const int bh   = blockIdx.x >> 3;
    const int h    = bh & 31;
    const int b    = bh >> 5;
    const int lane = threadIdx.x & 63;
    const int wm   = threadIdx.x >> 6;       // wave id = capsule within block
    const int l15  = lane & 15;
    const int l4   = lane >> 4;
    const int nb   = nblk * 64 + wm * 16;    // base output channel of this wave

    // acc[tap][nf]: C rows = 16 channels of capsule nb/16, cols = positions
    f32x4 acc[9][2];
    #pragma unroll
    for (int tap = 0; tap < 9; tap++) {
        f32x4 bv = *(const f32x4*)(bias + tap * NC + nb + l4 * 4);
        acc[tap][0] = bv;
        acc[tap][1] = bv;
    }

    // A (weights): row = nb+l15, k-chunk = l4 ; B (patches): col = pos, k-chunk = l4
    const __bf16* aptr = wT + ((size_t)(nb + l15)) * CIN + l4 * 8;
    const __bf16* bptr = inT + (((size_t)(b * INT_H + h) * INT_W) + l15) * CIN + l4 * 8;

    #pragma unroll
    for (int i = 0; i < 3; i++) {
        #pragma unroll
        for (int j = 0; j < 3; j++) {
            #pragma unroll
            for (int kk = 0; kk < 4; kk++) {
                bf16x8 a = *(const bf16x8*)(aptr + (size_t)((i * 3 + j) * NC) * CIN + kk * 32);
                #pragma unroll
                for (int nf = 0; nf < 2; nf++) {
                    bf16x8 bb_ = *(const bf16x8*)(bptr + (size_t)((i * INT_W) + j + nf * 16) * CIN + kk * 32);
                    acc[i * 3 + j][nf] =
                        __builtin_amdgcn_mfma_f32_16x16x32_bf16(a, bb_, acc[i * 3 + j][nf], 0, 0, 0);
                }
            }
        }
    }

    // ---- routing: channels live on rows -> 4 in-reg + shfl_xor(16,32) reduce ----
    f32x4 o[2];
    #pragma unroll
    for (int nf = 0; nf < 2; nf++) {
        f32x4 s = acc[0][nf];
        #pragma unroll
        for (int tap = 1; tap < 9; tap++) s += acc[tap][nf];
        o[nf] = s * (1.0f / 9.0f);
    }
    #pragma unroll
    for (int it = 0; it < 3; it++) {
        #pragma unroll
        for (int nf = 0; nf < 2; nf++) {
            float cw[9];
            float S = 0.f;
            #pragma unroll
            for (int tap = 0; tap < 9; tap++) {
                f32x4 d = o[nf] - acc[tap][nf];
                float d2 = d[0] * d[0] + d[1] * d[1] + d[2] * d[2] + d[3] * d[3];
                d2 += __shfl_xor(d2, 16);
                d2 += __shfl_xor(d2, 32);
                float r = __builtin_amdgcn_rsqf(d2 + 1e-4f);
                cw[tap] = r;
                S += r;
            }
            float inv = __builtin_amdgcn_rcpf(S);
            f32x4 on = acc[0][nf] * cw[0];
            #pragma unroll
            for (int tap = 1; tap < 9; tap++) on += acc[tap][nf] * cw[tap];
            o[nf] = on * inv;
        }
    }

    // ---- store: out[b][n][h][w], n = nb + l4*4 + reg, w = nf*16 + l15 ----
    size_t obase = ((size_t)(b * NC + nb + l4 * 4) * HW + h) * HW + l15;
    #pragma unroll
    for (int nf = 0; nf < 2; nf++)
        #pragma unroll
        for (int reg = 0; reg < 4; reg++)
            out[obase + (size_t)reg * HW * HW + nf * 16] = o[nf][reg];
}

extern "C" void kernel_launch(void* const* d_in, const int* in_sizes, int n_in,
                              void* d_out, int out_size, void* d_ws, size_t ws_size,
                              hipStream_t stream) {
    const float* in   = (const float*)d_in[0];
    const float* wgt  = (const float*)d_in[1];
    const float* bias = (const float*)d_in[2];
    float* out = (float*)d_out;

    __bf16* wT  = (__bf16*)d_ws;
    __bf16* inT = wT + WT_ELEMS;

    // zero-fill inT (borders must be 0; interior overwritten below)
    hipMemsetAsync(inT, 0, (size_t)INT_ELEMS * sizeof(__bf16), stream);

    transpose_w <<<288, 256, 0, stream>>>(wgt, wT);
    transpose_in<<<512, 256, 0, stream>>>(in, inT);

    dim3 grid(256 * 8);   // (b,h) rows x 8 channel-blocks
    caps_main<<<grid, 256, 0, stream>>>(wT, inT, bias, out);
}

// Round 4
// 59.695 us; speedup vs baseline: 4.6311x; 1.9892x over previous
//
#include <hip/hip_runtime.h>

// CapsuleLayer via bf16 MFMA + LDS-staged patches.
// Fixed sizes: B=8, C=128, H=W=32, K=3, pad=1 -> oh=ow=32, NC=512, 3 routing iters.
//
// d_ws layout:
//   wT  : bf16 [9][512][128]    (weights, k(ch)-contiguous)            589824 elems
//   inT : bf16 [8][34][34][128] (input, ch-last, padded, XOR-swizzled) 1183744 elems
// Swizzle: within each 256B channel-block of cell pos, byte ^= (pos&7)<<4.

typedef __bf16 bf16x8 __attribute__((ext_vector_type(8)));
typedef float  f32x4  __attribute__((ext_vector_type(4)));

#define NC    512
#define CIN   128
#define HW    32
#define BB    8
#define INT_H 34
#define INT_W 34
#define ROWB  (INT_W * CIN * 2)     // 8704 bytes per padded h-row
#define WT_ELEMS  (9 * NC * CIN)    // 589824
#define INT_ELEMS (BB * INT_H * INT_W * CIN)

// ---- pre-pass 1: wT[tap][n][ch] bf16 <- wgt[tap][ch][n] fp32 ----
__global__ __launch_bounds__(256)
void transpose_w(const float* __restrict__ wgt, __bf16* __restrict__ wT) {
    int g   = blockIdx.x * 256 + threadIdx.x;   // 73728 threads
    int n   = g & 511;
    int cb  = (g >> 9) & 15;
    int tap = g >> 13;
    bf16x8 v;
    #pragma unroll
    for (int k = 0; k < 8; k++)
        v[k] = (__bf16)wgt[(tap * CIN + cb * 8 + k) * NC + n];
    *(bf16x8*)(wT + ((size_t)tap * NC + n) * CIN + cb * 8) = v;
}

// ---- pre-pass 2: swizzled inT <- input[b][ch][h][w] fp32 ----
__global__ __launch_bounds__(256)
void transpose_in(const float* __restrict__ in, __bf16* __restrict__ inT) {
    int g  = blockIdx.x * 256 + threadIdx.x;    // 131072 threads
    int w  = g & 31;
    int h  = (g >> 5) & 31;
    int cb = (g >> 10) & 15;
    int b  = g >> 14;
    bf16x8 v;
    #pragma unroll
    for (int k = 0; k < 8; k++)
        v[k] = (__bf16)in[((b * CIN + cb * 8 + k) * HW + h) * HW + w];
    int pos = w + 1;
    size_t rowbase = ((size_t)(b * INT_H + h + 1) * INT_W) * 256;  // bytes
    int within = (cb * 16) ^ ((pos & 7) << 4);
    *(bf16x8*)((char*)inT + rowbase + pos * 256 + within) = v;
}

// ---- main: block = 64 channels (4 capsules, 1/wave) x 32 positions (one h-row) ----
__global__ __launch_bounds__(256, 3)
void caps_main(const __bf16* __restrict__ wT, const __bf16* __restrict__ inT,
               const float* __restrict__ bias, float* __restrict__ out) {
    __shared__ __attribute__((aligned(16))) unsigned char brow[3 * ROWB];  // 26112 B

    const int nblk = blockIdx.x & 7;
    const int bh   = blockIdx.x >> 3;
    const int h    = bh & 31;
    const int b    = bh >> 5;
    const int t    = threadIdx.x;
    const int lane = t & 63;
    const int wm   = t >> 6;
    const int l15  = lane & 15;
    const int l4   = lane >> 4;
    const int nb   = nblk * 64 + wm * 16;

    // ---- stage 3 contiguous (pre-swizzled) inT rows into LDS, linear dest ----
    // region = inT rows [h, h+2] padded coords = 26112 B contiguous
    const char* src = (const char*)inT + ((size_t)(b * INT_H + h) * INT_W) * 256;
    #pragma unroll
    for (int i = 0; i < 7; i++) {
        int c = wm + i * 4;                     // 1KB chunk id, 0..27
        if (c < 25) {
            __builtin_amdgcn_global_load_lds((const unsigned*)(src + c * 1024 + lane * 16),
                                             (unsigned*)(brow + c * 1024), 16, 0, 0);
        } else if (c == 25 && lane < 32) {      // tail 512 B
            __builtin_amdgcn_global_load_lds((const unsigned*)(src + c * 1024 + lane * 16),
                                             (unsigned*)(brow + c * 1024), 16, 0, 0);
        }
    }
    __syncthreads();

    // ---- priors: 9 taps x (16 ch x 32 pos) per wave, A from global, B from LDS ----
    f32x4 acc[9][2];
    #pragma unroll
    for (int tap = 0; tap < 9; tap++) {
        f32x4 bv = *(const f32x4*)(bias + tap * NC + nb + l4 * 4);
        acc[tap][0] = bv;
        acc[tap][1] = bv;
    }

    const __bf16* aptr = wT + ((size_t)(nb + l15)) * CIN + l4 * 8;

    #pragma unroll
    for (int i = 0; i < 3; i++) {
        #pragma unroll
        for (int j = 0; j < 3; j++) {
            const int tap = i * 3 + j;
            #pragma unroll
            for (int kk = 0; kk < 4; kk++) {
                bf16x8 a = *(const bf16x8*)(aptr + (size_t)(tap * NC) * CIN + kk * 32);
                #pragma unroll
                for (int nf = 0; nf < 2; nf++) {
                    int pos = j + nf * 16 + l15;
                    int off = i * ROWB + pos * 256 + ((kk * 64 + l4 * 16) ^ ((pos & 7) << 4));
                    bf16x8 bv = *(const bf16x8*)(brow + off);
                    acc[tap][nf] =
                        __builtin_amdgcn_mfma_f32_16x16x32_bf16(a, bv, acc[tap][nf], 0, 0, 0);
                }
            }
        }
    }

    // ---- routing: channels on C rows -> 4 in-reg + shfl_xor(16,32) reduce ----
    f32x4 o[2];
    #pragma unroll
    for (int nf = 0; nf < 2; nf++) {
        f32x4 s = acc[0][nf];
        #pragma unroll
        for (int tap = 1; tap < 9; tap++) s += acc[tap][nf];
        o[nf] = s * (1.0f / 9.0f);
    }
    #pragma unroll
    for (int it = 0; it < 3; it++) {
        #pragma unroll
        for (int nf = 0; nf < 2; nf++) {
            float cw[9];
            float S = 0.f;
            #pragma unroll
            for (int tap = 0; tap < 9; tap++) {
                f32x4 d = o[nf] - acc[tap][nf];
                float d2 = d[0] * d[0] + d[1] * d[1] + d[2] * d[2] + d[3] * d[3];
                d2 += __shfl_xor(d2, 16);
                d2 += __shfl_xor(d2, 32);
                float r = __builtin_amdgcn_rsqf(d2 + 1e-4f);
                cw[tap] = r;
                S += r;
            }
            float inv = __builtin_amdgcn_rcpf(S);
            f32x4 on = acc[0][nf] * cw[0];
            #pragma unroll
            for (int tap = 1; tap < 9; tap++) on += acc[tap][nf] * cw[tap];
            o[nf] = on * inv;
        }
    }

    // ---- store: out[b][n][h][w], n = nb + l4*4 + reg, w = nf*16 + l15 ----
    size_t obase = ((size_t)(b * NC + nb + l4 * 4) * HW + h) * HW + l15;
    #pragma unroll
    for (int nf = 0; nf < 2; nf++)
        #pragma unroll
        for (int reg = 0; reg < 4; reg++)
            out[obase + (size_t)reg * HW * HW + nf * 16] = o[nf][reg];
}

extern "C" void kernel_launch(void* const* d_in, const int* in_sizes, int n_in,
                              void* d_out, int out_size, void* d_ws, size_t ws_size,
                              hipStream_t stream) {
    const float* in   = (const float*)d_in[0];
    const float* wgt  = (const float*)d_in[1];
    const float* bias = (const float*)d_in[2];
    float* out = (float*)d_out;

    __bf16* wT  = (__bf16*)d_ws;
    __bf16* inT = wT + WT_ELEMS;

    hipMemsetAsync(inT, 0, (size_t)INT_ELEMS * sizeof(__bf16), stream);
    transpose_w <<<288, 256, 0, stream>>>(wgt, wT);
    transpose_in<<<512, 256, 0, stream>>>(in, inT);

    dim3 grid(256 * 8);   // (b,h) rows x 8 channel-blocks
    caps_main<<<grid, 256, 0, stream>>>(wT, inT, bias, out);
}